// Round 4
// baseline (148.604 us; speedup 1.0000x reference)
//
#include <hip/hip_runtime.h>

#define NTOK 32768
#define CDIM 256
#define KCODE 1024
#define C4 64   // CDIM/4

typedef __bf16 bf16x8 __attribute__((ext_vector_type(8)));
typedef float  f32x4  __attribute__((ext_vector_type(4)));
typedef const __attribute__((address_space(1))) void* as1cvp;
typedef __attribute__((address_space(3))) void* as3vp;

__device__ __forceinline__ unsigned long long umin64(unsigned long long a, unsigned long long b) { return a < b ? a : b; }
__device__ __forceinline__ unsigned long long umax64(unsigned long long a, unsigned long long b) { return a > b ? a : b; }

// ---------------- K1: normalize codebook -> en fp32, en2, eh/el bf16 --------
__global__ void k_norm_emb(const float* __restrict__ emb,
                           float* __restrict__ en, float* __restrict__ en2,
                           __bf16* __restrict__ eh, __bf16* __restrict__ el) {
    int k = blockIdx.x;
    int l = threadIdx.x;               // 64 lanes, 4 floats each
    float4 v = reinterpret_cast<const float4*>(emb)[k * C4 + l];
    float ss = v.x*v.x + v.y*v.y + v.z*v.z + v.w*v.w;
    #pragma unroll
    for (int o = 32; o >= 1; o >>= 1) ss += __shfl_xor(ss, o, 64);
    float den = fmaxf(sqrtf(ss), 1e-12f);
    float4 e;
    e.x = v.x / den; e.y = v.y / den; e.z = v.z / den; e.w = v.w / den;
    reinterpret_cast<float4*>(en)[k * C4 + l] = e;
    float s2 = e.x*e.x + e.y*e.y + e.z*e.z + e.w*e.w;
    #pragma unroll
    for (int o = 32; o >= 1; o >>= 1) s2 += __shfl_xor(s2, o, 64);
    if (l == 0) en2[k] = s2;

    __bf16* ehp = eh + (size_t)k * CDIM + 4 * l;
    __bf16* elp = el + (size_t)k * CDIM + 4 * l;
    float ev[4] = {e.x, e.y, e.z, e.w};
    #pragma unroll
    for (int q = 0; q < 4; ++q) {
        __bf16 h = (__bf16)ev[q];
        ehp[q] = h;
        elp[q] = (__bf16)(ev[q] - (float)h);
    }
}

// ---------------- K2: transpose+normalize z -> znt fp32 + znt2 --------------
__global__ void k_norm_z(const float* __restrict__ z,
                         float* __restrict__ znt, float* __restrict__ znt2) {
    __shared__ float zsb[CDIM * 32];   // 32 KB, [c][ (tok+c)&31 ]
    __shared__ float ssp[256];
    __shared__ float dens[32];
    int tid = threadIdx.x;
    int t0  = blockIdx.x * 32;
    int n   = t0 >> 10;
    int thw0 = t0 & 1023;

    int l = tid & 31, grp = tid >> 5;          // 8 c-stripes
    const float* zb = z + (((size_t)(n * CDIM)) << 10) + thw0 + l;
    float ss = 0.f;
    int c0 = grp * 32;
    for (int cc = 0; cc < 32; ++cc) {
        int c = c0 + cc;
        float v = zb[((size_t)c) << 10];
        zsb[c * 32 + ((l + c) & 31)] = v;
        ss += v * v;
    }
    ssp[tid] = ss;
    __syncthreads();
    if (tid < 32) {
        float tot = 0.f;
        #pragma unroll
        for (int g = 0; g < 8; ++g) tot += ssp[g * 32 + tid];
        dens[tid] = fmaxf(sqrtf(tot), 1e-12f);
    }
    __syncthreads();

    int l2 = tid & 63, tg = tid >> 6;          // 4 token-groups of 8
    for (int it = 0; it < 8; ++it) {
        int tok = tg * 8 + it;
        float den = dens[tok];
        float s2 = 0.f;
        #pragma unroll
        for (int cq = 0; cq < 4; ++cq) {
            int c = cq * 64 + l2;
            float v = zsb[c * 32 + ((tok + c) & 31)] / den;
            znt[((size_t)(t0 + tok)) * CDIM + c] = v;
            s2 += v * v;
        }
        #pragma unroll
        for (int o = 32; o >= 1; o >>= 1) s2 += __shfl_xor(s2, o, 64);
        if (l2 == 0) znt2[t0 + tok] = s2;
    }
}

// ---------------- K3: split-bf16 MFMA GEMM + top-2 (deferred epilogue) ------
// 256 blocks x 512 threads (8 waves: 4M x 2N). BM=128 tokens, 16 chunks of 64
// codes. A read from fp32 znt once, split hi/lo in regs. B (eh/el) staged to
// LDS via global_load_lds (pre-swizzled source), double-buffered. Selection
// epilogue of chunk ch-1 interleaved into MFMA issue gaps of chunk ch.
__global__ __launch_bounds__(512, 2) void k_mfma(
        const float* __restrict__ znt,
        const __bf16* __restrict__ eh, const __bf16* __restrict__ el,
        const float* __restrict__ en2g, uint2* __restrict__ top2) {
    __shared__ __bf16 ebuf[2][2][64 * 256];    // [buf][h/l], 32KB each = 128KB
    __shared__ float en2s[KCODE];              // 4KB
    __shared__ unsigned long long t2l[128][2][2];

    int tid = threadIdx.x;
    int l = tid & 63, wid = tid >> 6;
    int mw = wid >> 1, nw = wid & 1;           // 4M x 2N
    int t0 = blockIdx.x * 128;
    int row = l & 15, kg = l >> 4;             // frag row / k-group

    for (int i = tid; i < KCODE; i += 512) en2s[i] = en2g[i];

    // hoist A from fp32 znt, split hi/lo: 2 mt x 8 ks x {h,l}
    bf16x8 ah[2][8], al_[2][8];
    #pragma unroll
    for (int mt = 0; mt < 2; ++mt) {
        size_t tok = (size_t)(t0 + mw * 32 + mt * 16 + row);
        const float* pz = znt + tok * CDIM + kg * 8;
        #pragma unroll
        for (int ks = 0; ks < 8; ++ks) {
            float f[8];
            *reinterpret_cast<float4*>(&f[0]) = *reinterpret_cast<const float4*>(pz + ks * 32);
            *reinterpret_cast<float4*>(&f[4]) = *reinterpret_cast<const float4*>(pz + ks * 32 + 4);
            bf16x8 h, lo;
            #pragma unroll
            for (int q = 0; q < 8; ++q) {
                __bf16 hv = (__bf16)f[q];
                h[q] = hv;
                lo[q] = (__bf16)(f[q] - (float)hv);
            }
            ah[mt][ks] = h; al_[mt][ks] = lo;
        }
    }

    unsigned long long b1[8], b2[8];
    #pragma unroll
    for (int i = 0; i < 8; ++i) { b1[i] = ~0ull; b2[i] = ~0ull; }

    // stage one 64-code chunk (hi+lo) into ebuf[buf] with XOR swizzle.
    auto stage = [&](int buf, int ch) {
        #pragma unroll
        for (int a = 0; a < 2; ++a) {
            const __bf16* src = a ? el : eh;
            #pragma unroll
            for (int i2 = 0; i2 < 4; ++i2) {
                int s = i2 * 512 + tid;
                int code = s >> 5, c16 = s & 31;
                int gslot = c16 ^ (code & 15);
                const __bf16* gp = src + ((size_t)(ch * 64 + code)) * CDIM + gslot * 8;
                __bf16* ld = &ebuf[buf][a][0] + ((size_t)(i2 * 512 + wid * 64)) * 8;
                __builtin_amdgcn_global_load_lds((as1cvp)gp, (as3vp)ld, 16, 0, 0);
            }
        }
    };

    // one chunk: MFMA into acc; epilogue of accP (chunk chP) in the gaps
    auto body = [&](int ch, int buf, f32x4 (&acc)[2][2], f32x4 (&accP)[2][2],
                    int chP, bool doEpi, bool doStage) {
        if (doStage) stage(buf ^ 1, ch + 1);
        #pragma unroll
        for (int mt = 0; mt < 2; ++mt)
            #pragma unroll
            for (int nt = 0; nt < 2; ++nt)
                #pragma unroll
                for (int r = 0; r < 4; ++r) acc[mt][nt][r] = 0.f;

        float e2v[2] = {0.f, 0.f};
        if (doEpi) {
            e2v[0] = en2s[chP * 64 + nw * 32 + row];
            e2v[1] = en2s[chP * 64 + nw * 32 + 16 + row];
        }

        #pragma unroll
        for (int ks = 0; ks < 8; ++ks) {
            int c16 = ks * 4 + kg;
            bf16x8 bh[2], bl[2];
            #pragma unroll
            for (int nt = 0; nt < 2; ++nt) {
                int code = nw * 32 + nt * 16 + row;
                int slot = c16 ^ (code & 15);
                bh[nt] = *reinterpret_cast<const bf16x8*>(&ebuf[buf][0][code * 256 + slot * 8]);
                bl[nt] = *reinterpret_cast<const bf16x8*>(&ebuf[buf][1][code * 256 + slot * 8]);
            }
            #pragma unroll
            for (int mt = 0; mt < 2; ++mt)
                #pragma unroll
                for (int nt = 0; nt < 2; ++nt) {
                    acc[mt][nt] = __builtin_amdgcn_mfma_f32_16x16x32_bf16(ah[mt][ks],  bh[nt], acc[mt][nt], 0, 0, 0);
                    acc[mt][nt] = __builtin_amdgcn_mfma_f32_16x16x32_bf16(ah[mt][ks],  bl[nt], acc[mt][nt], 0, 0, 0);
                    acc[mt][nt] = __builtin_amdgcn_mfma_f32_16x16x32_bf16(al_[mt][ks], bh[nt], acc[mt][nt], 0, 0, 0);
                }
            if (doEpi) {
                #pragma unroll
                for (int pp = 0; pp < 2; ++pp) {
                    int p = ks * 2 + pp;
                    int nt = p >> 3, rem = p & 7, mt = rem >> 2, r = rem & 3;
                    float d = fmaf(-2.0f, accP[mt][nt][r], e2v[nt]);
                    unsigned ub = __float_as_uint(d);
                    ub ^= ((unsigned)((int)ub >> 31)) | 0x80000000u;
                    int code = chP * 64 + nw * 32 + nt * 16 + row;
                    unsigned long long key = ((unsigned long long)ub << 32) | (unsigned)code;
                    int idx = mt * 4 + r;
                    if (key < b1[idx]) { b2[idx] = b1[idx]; b1[idx] = key; }
                    else if (key < b2[idx]) { b2[idx] = key; }
                }
            }
        }
    };

    f32x4 accA[2][2], accB[2][2];
    stage(0, 0);
    __syncthreads();

    body(0, 0, accA, accB, 0, false, true);
    __syncthreads();
    #pragma unroll 1
    for (int i = 0; i < 7; ++i) {
        int ch = 1 + 2 * i;
        body(ch, 1, accB, accA, ch - 1, true, true);
        __syncthreads();
        body(ch + 1, 0, accA, accB, ch, true, true);
        __syncthreads();
    }
    body(15, 1, accB, accA, 14, true, false);

    // tail epilogue: chunk 15 from accB
    {
        float e2v[2] = {en2s[15 * 64 + nw * 32 + row], en2s[15 * 64 + nw * 32 + 16 + row]};
        #pragma unroll
        for (int p = 0; p < 16; ++p) {
            int nt = p >> 3, rem = p & 7, mt = rem >> 2, r = rem & 3;
            float d = fmaf(-2.0f, accB[mt][nt][r], e2v[nt]);
            unsigned ub = __float_as_uint(d);
            ub ^= ((unsigned)((int)ub >> 31)) | 0x80000000u;
            int code = 15 * 64 + nw * 32 + nt * 16 + row;
            unsigned long long key = ((unsigned long long)ub << 32) | (unsigned)code;
            int idx = mt * 4 + r;
            if (key < b1[idx]) { b2[idx] = b1[idx]; b1[idx] = key; }
            else if (key < b2[idx]) { b2[idx] = key; }
        }
    }

    // butterfly top-2 merge across the 16 col-lanes
    #pragma unroll
    for (int i = 0; i < 8; ++i) {
        #pragma unroll
        for (int off = 1; off < 16; off <<= 1) {
            unsigned long long o1 = __shfl_xor(b1[i], off, 64);
            unsigned long long o2 = __shfl_xor(b2[i], off, 64);
            unsigned long long m1 = umin64(b1[i], o1);
            unsigned long long m2 = umin64(umax64(b1[i], o1), umin64(b2[i], o2));
            b1[i] = m1; b2[i] = m2;
        }
    }
    if ((l & 15) == 0) {
        #pragma unroll
        for (int mt = 0; mt < 2; ++mt)
            #pragma unroll
            for (int r = 0; r < 4; ++r) {
                int tl = mw * 32 + mt * 16 + kg * 4 + r;   // C/D row mapping
                t2l[tl][nw][0] = b1[mt * 4 + r];
                t2l[tl][nw][1] = b2[mt * 4 + r];
            }
    }
    __syncthreads();
    if (tid < 128) {
        unsigned long long a1 = t2l[tid][0][0], a2 = t2l[tid][0][1];
        unsigned long long c1 = t2l[tid][1][0], c2 = t2l[tid][1][1];
        unsigned long long m1 = umin64(a1, c1);
        unsigned long long m2 = umin64(umax64(a1, c1), umin64(a2, c2));
        top2[t0 + tid] = make_uint2((unsigned)m1, (unsigned)m2);
    }
}

// ---------------- K3b: fp32 fixup of top-2 candidates -----------------------
__global__ void k_fixup(const float* __restrict__ znt, const float* __restrict__ znt2,
                        const float* __restrict__ en,  const float* __restrict__ en2,
                        const uint2* __restrict__ top2,
                        int* __restrict__ idxb, float* __restrict__ idxf) {
    int tid = threadIdx.x;
    int l = tid & 63, wid = tid >> 6;
    int t = blockIdx.x * 4 + wid;
    uint2 cd = top2[t];
    float4 z4 = reinterpret_cast<const float4*>(znt)[(size_t)t * C4 + l];
    float4 ea = reinterpret_cast<const float4*>(en)[(size_t)cd.x * C4 + l];
    float4 eb = reinterpret_cast<const float4*>(en)[(size_t)cd.y * C4 + l];
    float da = z4.x*ea.x + z4.y*ea.y + z4.z*ea.z + z4.w*ea.w;
    float db = z4.x*eb.x + z4.y*eb.y + z4.z*eb.z + z4.w*eb.w;
    #pragma unroll
    for (int o = 32; o >= 1; o >>= 1) {
        da += __shfl_xor(da, o, 64);
        db += __shfl_xor(db, o, 64);
    }
    if (l == 0) {
        float z2 = znt2[t];
        float d1 = (z2 + en2[cd.x]) - 2.0f * da;
        float d2 = (z2 + en2[cd.y]) - 2.0f * db;
        int k = (d2 < d1 || (d2 == d1 && cd.y < cd.x)) ? (int)cd.y : (int)cd.x;
        idxb[t] = k;
        idxf[t] = (float)k;
    }
}

// ---------------- K4: gather epilogue (quant = emb[idx], NCHW) --------------
__global__ void k_gather(const float* __restrict__ emb,
                         const int* __restrict__ idxb, float* __restrict__ out) {
    int o  = blockIdx.x * 256 + threadIdx.x;
    int hw = o & 1023;
    int nc = o >> 10;
    int c  = nc & 255;
    int n  = nc >> 8;
    int t  = (n << 10) | hw;
    int k  = idxb[t];
    out[o] = emb[(size_t)k * CDIM + c];
}

extern "C" void kernel_launch(void* const* d_in, const int* in_sizes, int n_in,
                              void* d_out, int out_size, void* d_ws, size_t ws_size,
                              hipStream_t stream) {
    const float* z   = (const float*)d_in[0];
    const float* emb = (const float*)d_in[1];
    float* out  = (float*)d_out;
    float* znt  = out;                          // quant region doubles as zn scratch
    float* idxf = out + (size_t)NTOK * CDIM;    // index output (float) tail

    float*  en   = (float*)d_ws;                        // 1 MB
    float*  en2  = en + (size_t)KCODE * CDIM;           // 4 KB
    float*  znt2 = en2 + KCODE;                         // 128 KB
    __bf16* eh   = (__bf16*)(znt2 + NTOK);              // 512 KB
    __bf16* el   = eh + (size_t)KCODE * CDIM;           // 512 KB
    uint2*  top2 = (uint2*)(el + (size_t)KCODE * CDIM); // 256 KB
    int*    idxb = (int*)(top2 + NTOK);                 // 128 KB

    k_norm_emb<<<KCODE, 64, 0, stream>>>(emb, en, en2, eh, el);
    k_norm_z<<<NTOK / 32, 256, 0, stream>>>(z, znt, znt2);
    k_mfma<<<NTOK / 128, 512, 0, stream>>>(znt, eh, el, en2, top2);
    k_fixup<<<NTOK / 4, 256, 0, stream>>>(znt, znt2, en, en2, top2, idxb, idxf);
    k_gather<<<(NTOK * CDIM) / 256, 256, 0, stream>>>(emb, idxb, out);
}

// Round 5
// 128.849 us; speedup vs baseline: 1.1533x; 1.1533x over previous
//
#include <hip/hip_runtime.h>

#define NTOK 32768
#define CDIM 256
#define KCODE 1024
#define C4 64   // CDIM/4

typedef __bf16 bf16x8 __attribute__((ext_vector_type(8)));
typedef float  f32x4  __attribute__((ext_vector_type(4)));
typedef const __attribute__((address_space(1))) void* as1cvp;
typedef __attribute__((address_space(3))) void* as3vp;

__device__ __forceinline__ unsigned long long umin64(unsigned long long a, unsigned long long b) { return a < b ? a : b; }
__device__ __forceinline__ unsigned long long umax64(unsigned long long a, unsigned long long b) { return a > b ? a : b; }

// ---------------- K1: normalize codebook -> en fp32, en2, eh/el bf16 --------
__global__ void k_norm_emb(const float* __restrict__ emb,
                           float* __restrict__ en, float* __restrict__ en2,
                           __bf16* __restrict__ eh, __bf16* __restrict__ el) {
    int k = blockIdx.x;
    int l = threadIdx.x;               // 64 lanes, 4 floats each
    float4 v = reinterpret_cast<const float4*>(emb)[k * C4 + l];
    float ss = v.x*v.x + v.y*v.y + v.z*v.z + v.w*v.w;
    #pragma unroll
    for (int o = 32; o >= 1; o >>= 1) ss += __shfl_xor(ss, o, 64);
    float den = fmaxf(sqrtf(ss), 1e-12f);
    float4 e;
    e.x = v.x / den; e.y = v.y / den; e.z = v.z / den; e.w = v.w / den;
    reinterpret_cast<float4*>(en)[k * C4 + l] = e;
    float s2 = e.x*e.x + e.y*e.y + e.z*e.z + e.w*e.w;
    #pragma unroll
    for (int o = 32; o >= 1; o >>= 1) s2 += __shfl_xor(s2, o, 64);
    if (l == 0) en2[k] = s2;

    __bf16* ehp = eh + (size_t)k * CDIM + 4 * l;
    __bf16* elp = el + (size_t)k * CDIM + 4 * l;
    float ev[4] = {e.x, e.y, e.z, e.w};
    #pragma unroll
    for (int q = 0; q < 4; ++q) {
        __bf16 h = (__bf16)ev[q];
        ehp[q] = h;
        elp[q] = (__bf16)(ev[q] - (float)h);
    }
}

// ---------------- K2: transpose+normalize z -> znt fp32, znt2, zh/zl bf16 ---
__global__ void k_norm_z(const float* __restrict__ z,
                         float* __restrict__ znt, float* __restrict__ znt2,
                         __bf16* __restrict__ zh, __bf16* __restrict__ zl) {
    __shared__ float zsb[CDIM * 32];   // 32 KB, [c][ (tok+c)&31 ]
    __shared__ float ssp[256];
    __shared__ float dens[32];
    int tid = threadIdx.x;
    int t0  = blockIdx.x * 32;
    int n   = t0 >> 10;
    int thw0 = t0 & 1023;

    int l = tid & 31, grp = tid >> 5;          // 8 c-stripes
    const float* zb = z + (((size_t)(n * CDIM)) << 10) + thw0 + l;
    float ss = 0.f;
    int c0 = grp * 32;
    for (int cc = 0; cc < 32; ++cc) {
        int c = c0 + cc;
        float v = zb[((size_t)c) << 10];
        zsb[c * 32 + ((l + c) & 31)] = v;
        ss += v * v;
    }
    ssp[tid] = ss;
    __syncthreads();
    if (tid < 32) {
        float tot = 0.f;
        #pragma unroll
        for (int g = 0; g < 8; ++g) tot += ssp[g * 32 + tid];
        dens[tid] = fmaxf(sqrtf(tot), 1e-12f);
    }
    __syncthreads();

    int l2 = tid & 63, tg = tid >> 6;          // 4 token-groups of 8
    for (int it = 0; it < 8; ++it) {
        int tok = tg * 8 + it;
        float den = dens[tok];
        float s2 = 0.f;
        #pragma unroll
        for (int cq = 0; cq < 4; ++cq) {
            int c = cq * 64 + l2;
            float v = zsb[c * 32 + ((tok + c) & 31)] / den;
            size_t off = ((size_t)(t0 + tok)) * CDIM + c;
            znt[off] = v;
            __bf16 h = (__bf16)v;
            zh[off] = h;
            zl[off] = (__bf16)(v - (float)h);
            s2 += v * v;
        }
        #pragma unroll
        for (int o = 32; o >= 1; o >>= 1) s2 += __shfl_xor(s2, o, 64);
        if (l2 == 0) znt2[t0 + tok] = s2;
    }
}

// ---------------- K3: split-bf16 MFMA GEMM + top-2 selection ----------------
// 512 blocks x 256 threads (4 waves: 2M x 2N). BM=64 tokens/block, 1024 codes
// in 32 chunks of 32. ~70KB LDS -> 2 blocks/CU: cross-block overlap hides the
// per-chunk barrier drain. A (zh/zl) in regs; B (eh/el) double-buffered in
// LDS via global_load_lds with pre-swizzled source.
__global__ __launch_bounds__(256, 2) void k_mfma(
        const __bf16* __restrict__ zh, const __bf16* __restrict__ zl,
        const __bf16* __restrict__ eh, const __bf16* __restrict__ el,
        const float* __restrict__ en2g, uint2* __restrict__ top2) {
    __shared__ __bf16 ebuf[2][2][32 * 256];    // [buf][h/l], 16KB each = 64KB
    __shared__ float en2s[KCODE];              // 4KB
    __shared__ unsigned long long t2l[64][2][2];

    int tid = threadIdx.x;
    int l = tid & 63, wid = tid >> 6;
    int mw = wid >> 1, nw = wid & 1;           // 2M x 2N
    int t0 = blockIdx.x * 64;
    int row = l & 15, kg = l >> 4;             // frag row / k-group

    for (int i = tid; i < KCODE; i += 256) en2s[i] = en2g[i];

    // hoist A: 2 mtiles x 8 ksteps x {hi,lo} = 128 VGPR, z read once
    bf16x8 ah[2][8], al_[2][8];
    #pragma unroll
    for (int mt = 0; mt < 2; ++mt) {
        size_t tok = (size_t)(t0 + mw * 32 + mt * 16 + row);
        const __bf16* ph = zh + tok * CDIM + kg * 8;
        const __bf16* pl = zl + tok * CDIM + kg * 8;
        #pragma unroll
        for (int ks = 0; ks < 8; ++ks) {
            ah[mt][ks]  = *reinterpret_cast<const bf16x8*>(ph + ks * 32);
            al_[mt][ks] = *reinterpret_cast<const bf16x8*>(pl + ks * 32);
        }
    }

    // top-2 keys per lane-token: 2 mtiles x 4 regs
    unsigned long long b1[8], b2[8];
    #pragma unroll
    for (int i = 0; i < 8; ++i) { b1[i] = ~0ull; b2[i] = ~0ull; }

    // stage one 32-code chunk (hi+lo) into ebuf[buf] with XOR swizzle.
    // row = code (256 bf16 = 32 slots of 16B); stored slot = c16 ^ (code&15).
    auto stage = [&](int buf, int ch) {
        #pragma unroll
        for (int a = 0; a < 2; ++a) {
            const __bf16* src = a ? el : eh;
            #pragma unroll
            for (int i2 = 0; i2 < 4; ++i2) {
                int s = i2 * 256 + tid;
                int code = s >> 5, c16 = s & 31;
                int gslot = c16 ^ (code & 15);
                const __bf16* gp = src + ((size_t)(ch * 32 + code)) * CDIM + gslot * 8;
                __bf16* ld = &ebuf[buf][a][0] + ((size_t)(i2 * 256 + wid * 64)) * 8;
                __builtin_amdgcn_global_load_lds((as1cvp)gp, (as3vp)ld, 16, 0, 0);
            }
        }
    };

    stage(0, 0);
    __syncthreads();
    #pragma unroll 2
    for (int ch = 0; ch < 32; ++ch) {
        int cur = ch & 1;
        if (ch < 31) stage(cur ^ 1, ch + 1);

        const __bf16* bh_base = &ebuf[cur][0][0];
        const __bf16* bl_base = &ebuf[cur][1][0];

        f32x4 acc[2];
        #pragma unroll
        for (int mt = 0; mt < 2; ++mt)
            #pragma unroll
            for (int r = 0; r < 4; ++r) acc[mt][r] = 0.f;

        int code_l = nw * 16 + row;
        #pragma unroll
        for (int ks = 0; ks < 8; ++ks) {
            int slot = (ks * 4 + kg) ^ row;
            bf16x8 bh = *reinterpret_cast<const bf16x8*>(bh_base + code_l * 256 + slot * 8);
            bf16x8 bl = *reinterpret_cast<const bf16x8*>(bl_base + code_l * 256 + slot * 8);
            #pragma unroll
            for (int mt = 0; mt < 2; ++mt) {
                acc[mt] = __builtin_amdgcn_mfma_f32_16x16x32_bf16(ah[mt][ks],  bh, acc[mt], 0, 0, 0);
                acc[mt] = __builtin_amdgcn_mfma_f32_16x16x32_bf16(ah[mt][ks],  bl, acc[mt], 0, 0, 0);
                acc[mt] = __builtin_amdgcn_mfma_f32_16x16x32_bf16(al_[mt][ks], bh, acc[mt], 0, 0, 0);
            }
        }

        // selection epilogue: d' = e2 - 2*dot; code col = lane&15
        int code = ch * 32 + code_l;
        float e2v = en2s[code];
        #pragma unroll
        for (int mt = 0; mt < 2; ++mt)
            #pragma unroll
            for (int r = 0; r < 4; ++r) {
                float d = fmaf(-2.0f, acc[mt][r], e2v);
                unsigned ub = __float_as_uint(d);
                ub = (ub & 0x80000000u) ? ~ub : (ub | 0x80000000u);
                unsigned long long key = ((unsigned long long)ub << 32) | (unsigned)code;
                int idx = mt * 4 + r;
                if (key < b1[idx]) { b2[idx] = b1[idx]; b1[idx] = key; }
                else if (key < b2[idx]) { b2[idx] = key; }
            }
        __syncthreads();
    }

    // butterfly top-2 merge across the 16 code-col lanes
    #pragma unroll
    for (int i = 0; i < 8; ++i) {
        #pragma unroll
        for (int off = 1; off < 16; off <<= 1) {
            unsigned long long o1 = __shfl_xor(b1[i], off, 64);
            unsigned long long o2 = __shfl_xor(b2[i], off, 64);
            unsigned long long m1 = umin64(b1[i], o1);
            unsigned long long m2 = umin64(umax64(b1[i], o1), umin64(b2[i], o2));
            b1[i] = m1; b2[i] = m2;
        }
    }
    if ((l & 15) == 0) {
        #pragma unroll
        for (int mt = 0; mt < 2; ++mt)
            #pragma unroll
            for (int r = 0; r < 4; ++r) {
                int tl = mw * 32 + mt * 16 + kg * 4 + r;   // C/D row mapping
                t2l[tl][nw][0] = b1[mt * 4 + r];
                t2l[tl][nw][1] = b2[mt * 4 + r];
            }
    }
    __syncthreads();
    if (tid < 64) {
        unsigned long long a1 = t2l[tid][0][0], a2 = t2l[tid][0][1];
        unsigned long long c1 = t2l[tid][1][0], c2 = t2l[tid][1][1];
        unsigned long long m1 = umin64(a1, c1);
        unsigned long long m2 = umin64(umax64(a1, c1), umin64(a2, c2));
        top2[t0 + tid] = make_uint2((unsigned)m1, (unsigned)m2);
    }
}

// ---------------- K3b: fp32 fixup of top-2 candidates -----------------------
__global__ void k_fixup(const float* __restrict__ znt, const float* __restrict__ znt2,
                        const float* __restrict__ en,  const float* __restrict__ en2,
                        const uint2* __restrict__ top2,
                        int* __restrict__ idxb, float* __restrict__ idxf) {
    int tid = threadIdx.x;
    int l = tid & 63, wid = tid >> 6;
    int t = blockIdx.x * 4 + wid;
    uint2 cd = top2[t];
    float4 z4 = reinterpret_cast<const float4*>(znt)[(size_t)t * C4 + l];
    float4 ea = reinterpret_cast<const float4*>(en)[(size_t)cd.x * C4 + l];
    float4 eb = reinterpret_cast<const float4*>(en)[(size_t)cd.y * C4 + l];
    float da = z4.x*ea.x + z4.y*ea.y + z4.z*ea.z + z4.w*ea.w;
    float db = z4.x*eb.x + z4.y*eb.y + z4.z*eb.z + z4.w*eb.w;
    #pragma unroll
    for (int o = 32; o >= 1; o >>= 1) {
        da += __shfl_xor(da, o, 64);
        db += __shfl_xor(db, o, 64);
    }
    if (l == 0) {
        float z2 = znt2[t];
        float d1 = (z2 + en2[cd.x]) - 2.0f * da;
        float d2 = (z2 + en2[cd.y]) - 2.0f * db;
        int k = (d2 < d1 || (d2 == d1 && cd.y < cd.x)) ? (int)cd.y : (int)cd.x;
        idxb[t] = k;
        idxf[t] = (float)k;
    }
}

// ---------------- K4: gather epilogue (quant = emb[idx], NCHW) --------------
__global__ void k_gather(const float* __restrict__ emb,
                         const int* __restrict__ idxb, float* __restrict__ out) {
    int o  = blockIdx.x * 256 + threadIdx.x;
    int hw = o & 1023;
    int nc = o >> 10;
    int c  = nc & 255;
    int n  = nc >> 8;
    int t  = (n << 10) | hw;
    int k  = idxb[t];
    out[o] = emb[(size_t)k * CDIM + c];
}

extern "C" void kernel_launch(void* const* d_in, const int* in_sizes, int n_in,
                              void* d_out, int out_size, void* d_ws, size_t ws_size,
                              hipStream_t stream) {
    const float* z   = (const float*)d_in[0];
    const float* emb = (const float*)d_in[1];
    float* out  = (float*)d_out;
    float* znt  = out;                          // quant region doubles as zn scratch
    float* idxf = out + (size_t)NTOK * CDIM;    // index output (float) tail

    float*  en   = (float*)d_ws;                        // 1 MB
    float*  en2  = en + (size_t)KCODE * CDIM;           // 4 KB
    float*  znt2 = en2 + KCODE;                         // 128 KB
    __bf16* eh   = (__bf16*)(znt2 + NTOK);              // 512 KB
    __bf16* el   = eh + (size_t)KCODE * CDIM;           // 512 KB
    __bf16* zh   = el + (size_t)KCODE * CDIM;           // 16 MB
    __bf16* zl   = zh + (size_t)NTOK * CDIM;            // 16 MB
    uint2*  top2 = (uint2*)(zl + (size_t)NTOK * CDIM);  // 256 KB
    int*    idxb = (int*)(top2 + NTOK);                 // 128 KB

    k_norm_emb<<<KCODE, 64, 0, stream>>>(emb, en, en2, eh, el);
    k_norm_z<<<NTOK / 32, 256, 0, stream>>>(z, znt, znt2, zh, zl);
    k_mfma<<<NTOK / 64, 256, 0, stream>>>(zh, zl, eh, el, en2, top2);
    k_fixup<<<NTOK / 4, 256, 0, stream>>>(znt, znt2, en, en2, top2, idxb, idxf);
    k_gather<<<(NTOK * CDIM) / 256, 256, 0, stream>>>(emb, idxb, out);
}